// Round 14
// baseline (37.497 us; speedup 1.0000x reference)
//
#include <hip/hip_runtime.h>
#include <math.h>
#include <stdint.h>

#define CH 16
#define DIM 8
#define ROW 128            // CH*DIM
#define BLK 256            // 4 waves
#define ROWS_PER_BLOCK 128 // 8 wave-tiles of 16 rows (2 per wave)

typedef __attribute__((ext_vector_type(8))) short bf16x8;
typedef __attribute__((ext_vector_type(4))) float f32x4;
typedef __attribute__((ext_vector_type(4))) unsigned int u32x4;

// Cayley sign for Cl(3,0): e_a * e_b = csign(a,b) * e_{a^b}
__device__ __forceinline__ float csign(int a, int b) {
    int s = 0;
    int aa = a >> 1;
    while (aa) { s ^= (__popc(aa & b) & 1); aa >>= 1; }
    return s ? -1.0f : 1.0f;
}

// float -> bf16 (round-to-nearest-even)
__device__ __forceinline__ unsigned short f2bf(float f) {
    union { float f; unsigned u; } x; x.f = f;
    unsigned r = x.u + 0x7FFF + ((x.u >> 16) & 1);
    return (unsigned short)(r >> 16);
}

// Exact-GELU via odd Taylor poly for erf (|s|<=~1.02 after unit-norm rotor
// sandwich, ln_scale folded into D; poly err < 2e-6 on that domain).
__device__ __forceinline__ float gelu_poly(float s) {
    const float z = s * 0.70710678f;
    const float u = z * z;
    float p = -8.5483270e-04f;
    p = fmaf(p, u,  5.2239776e-03f);
    p = fmaf(p, u, -2.6866138e-02f);
    p = fmaf(p, u,  1.1283792e-01f);
    p = fmaf(p, u, -3.7612639e-01f);
    p = fmaf(p, u,  1.1283792e+00f);
    return 0.5f * s * fmaf(z, p, 1.0f);
}

// ---------------------------------------------------------------------------
// Precompute, grid=2 x 1024 threads:
//   block 0: D[f_out][f_in] bf16 block-diag rotor-sandwich (ln_scale folded)
//   block 1: W2R[out_f][in_f] bf16 128x128 CliffordLinear matrix
// ws as ushort*: u[0..16384) = D, u[16384..32768) = W2R
// ---------------------------------------------------------------------------
__global__ void precompute_kernel(const float* __restrict__ rotor,
                                  const float* __restrict__ w,
                                  const float* __restrict__ ln_scale,
                                  float* __restrict__ ws)
{
    const int t = threadIdx.x;
    unsigned short* D   = (unsigned short*)ws;
    unsigned short* w2r = D + 16384;

    if (blockIdx.x == 0) {
        ((u32x4*)D)[t]        = (u32x4){0u, 0u, 0u, 0u};
        ((u32x4*)D)[t + 1024] = (u32x4){0u, 0u, 0u, 0u};
        __syncthreads();

        if (t < CH) {
            const int c = t;
            float r[8];
            float nn = 0.f;
            #pragma unroll
            for (int i = 0; i < 8; ++i) { r[i] = rotor[c * 8 + i]; nn += r[i] * r[i]; }
            const float inv = rsqrtf(nn + 1e-6f);
            #pragma unroll
            for (int i = 0; i < 8; ++i) r[i] *= inv;

            const float REVv[8] = {1.f, 1.f, 1.f, -1.f, 1.f, -1.f, -1.f, -1.f};
            float rr[8];
            #pragma unroll
            for (int j = 0; j < 8; ++j) rr[j] = r[j] * REVv[j];

            float L[8][8], R[8][8];
            #pragma unroll
            for (int a = 0; a < 8; ++a)
                #pragma unroll
                for (int b = 0; b < 8; ++b) { L[a][b] = 0.f; R[a][b] = 0.f; }

            #pragma unroll
            for (int i = 0; i < 8; ++i)
                #pragma unroll
                for (int j = 0; j < 8; ++j) {
                    const float s = csign(i, j);
                    L[i ^ j][j] += r[i] * s;
                    R[i ^ j][i] += rr[j] * s;
                }

            const float sc = ln_scale[c];
            #pragma unroll
            for (int k = 0; k < 8; ++k)
                #pragma unroll
                for (int m = 0; m < 8; ++m) {
                    float acc = 0.f;
                    #pragma unroll
                    for (int i = 0; i < 8; ++i) acc += R[k][i] * L[i][m];
                    D[(c * 8 + k) * ROW + (c * 8 + m)] = f2bf(acc * sc);
                }
        }
    } else {
        #pragma unroll
        for (int task = t; task < ROW * CH; task += 1024) {
            const int outf = task >> 4;
            const int ci   = task & 15;
            const int kb = outf & 7, o = outf >> 3;
            const float4 w0 = *(const float4*)(w + (o * CH + ci) * 8);
            const float4 w1 = *(const float4*)(w + (o * CH + ci) * 8 + 4);
            const float wv[8] = {w0.x, w0.y, w0.z, w0.w, w1.x, w1.y, w1.z, w1.w};
            bf16x8 pk;
            #pragma unroll
            for (int j = 0; j < 8; ++j) {
                const int i = kb ^ j;
                pk[j] = (short)f2bf(wv[i] * csign(i, j));
            }
            *(bf16x8*)(w2r + outf * ROW + ci * 8) = pk;
        }
    }
}

// ---------------------------------------------------------------------------
// Fused, BARRIER-FREE wave-independent design (R12 lesson: fill kernels hit
// 84% HBM at 9% occupancy -- continuous memory issue, no lockstep). Each
// WAVE owns a 16-row tile end-to-end; the only block barrier is the one-time
// sW staging. R13 bug fixed: sW staging must copy 2048 chunks (128 cols x 16
// chunks), i.e. 8 iterations of 256 threads -- NOT 4 (half of sW was garbage).
//
// Per wave-tile (16 rows):
//  phase1: A-frag = own 16 rows, mfma vs block-diag D (regs) -> C transposed
//          [feature=lcol][rows lkg*4+j]; GELU -> wave-PRIVATE sG via
//          XOR-chunk transpose (write -> lgkmcnt(0), same wave, no s_barrier).
//  phase2: A from own sG; B from block-shared swizzled sW; 32 mfma ->
//          16x128 out rows.
// LDS: sW 32K + 4x4K sG = 48K -> 3 blocks/CU. launch_bounds(256,4) ONLY
// (R3/R8 twice-burned rule).
// ---------------------------------------------------------------------------
__global__ __launch_bounds__(BLK, 4) void fused_kernel(
        const float* __restrict__ x,
        const float* __restrict__ bias,
        const float* __restrict__ ws,
        float* __restrict__ out)
{
    __shared__ unsigned short sW[ROW * ROW];     // 32 KiB, XOR-chunk swizzled
    __shared__ unsigned short sG[4][16 * ROW];   // 4 KiB per wave, private

    const int t    = threadIdx.x;
    const int lane = t & 63;
    const int wave = t >> 6;
    const int lcol = lane & 15;
    const int lkg  = lane >> 4;

    const unsigned short* D   = (const unsigned short*)ws;
    const unsigned short* w2r = D + 16384;

    // ---- stage W2R -> sW with XOR-chunk swizzle (one time)
    // 128 cols x 16 chunks = 2048 chunks; 256 threads x 8 iters   [R13 fix]
    #pragma unroll
    for (int i = 0; i < 8; ++i) {
        const int idx   = t + i * BLK;       // 16B-chunk index, 2048 total
        const int col   = idx >> 4;
        const int ch    = idx & 15;
        const int chunk = ch ^ (col & 15);
        const bf16x8 v = *(const bf16x8*)(w2r + col * ROW + ch * 8);
        *(bf16x8*)(&sW[col * ROW + chunk * 8]) = v;
    }

    // ---- D fragments in regs: Df[g][h] covers feature-cols 32g+16h+lcol,
    //      K = 32g + lkg*8 (block-diag slice)
    bf16x8 Df[4][2];
    #pragma unroll
    for (int g = 0; g < 4; ++g)
        #pragma unroll
        for (int h = 0; h < 2; ++h) {
            const int col = 32 * g + 16 * h + lcol;
            Df[g][h] = *(const bf16x8*)(D + col * ROW + 32 * g + lkg * 8);
        }

    // ---- bias for the 8 col-tiles this lane stores
    float bv[8];
    #pragma unroll
    for (int ct = 0; ct < 8; ++ct) bv[ct] = bias[ct * 16 + lcol];

    __syncthreads();     // the ONLY block-wide barrier (sW visible)

    unsigned short* mG = &sG[wave][0];

    #pragma unroll
    for (int tt = 0; tt < 2; ++tt) {
        const size_t row0 = (size_t)blockIdx.x * ROWS_PER_BLOCK
                          + (tt * 4 + wave) * 16;

        // ---- load this tile's x: lane (lcol,lkg) = row lcol, channel 4g+lkg
        float4 xa[4], xb[4];
        #pragma unroll
        for (int g = 0; g < 4; ++g) {
            const float4* xp = (const float4*)(x + ((row0 + lcol) * CH + 4 * g + lkg) * DIM);
            xa[g] = xp[0];
            xb[g] = xp[1];
        }

        // ---- phase 1: LN -> rotor MFMA -> GELU -> transpose into own sG
        #pragma unroll
        for (int g = 0; g < 4; ++g) {
            const float4 a = xa[g], b = xb[g];
            const float nn = a.x*a.x + a.y*a.y + a.z*a.z + a.w*a.w
                           + b.x*b.x + b.y*b.y + b.z*b.z + b.w*b.w;
            const float inv = rsqrtf(nn + 1e-6f);
            bf16x8 af;
            af[0] = (short)f2bf(a.x * inv); af[1] = (short)f2bf(a.y * inv);
            af[2] = (short)f2bf(a.z * inv); af[3] = (short)f2bf(a.w * inv);
            af[4] = (short)f2bf(b.x * inv); af[5] = (short)f2bf(b.y * inv);
            af[6] = (short)f2bf(b.z * inv); af[7] = (short)f2bf(b.w * inv);

            #pragma unroll
            for (int h = 0; h < 2; ++h) {
                f32x4 p = (f32x4){0.f, 0.f, 0.f, 0.f};
                p = __builtin_amdgcn_mfma_f32_16x16x32_bf16(af, Df[g][h], p, 0, 0, 0);
                const int feat   = 32 * g + 16 * h + lcol;   // fixed per lane
                const int chunk0 = feat >> 3;                // 4g+2h+(lcol>>3)
                #pragma unroll
                for (int j = 0; j < 4; ++j) {
                    const float y = gelu_poly(p[j]);
                    const int row   = lkg * 4 + j;           // 0..15
                    const int chunk = chunk0 ^ row;
                    mG[row * ROW + chunk * 8 + (feat & 7)] = f2bf(y);
                }
            }
        }

        // wave-local write->read ordering; no s_barrier needed (private sG)
        asm volatile("s_waitcnt lgkmcnt(0)" ::: "memory");
        __builtin_amdgcn_sched_barrier(0);

        // ---- phase 2: 16 rows x 128 cols, K=128; B from shared sW
        f32x4 acc[8];
        #pragma unroll
        for (int ct = 0; ct < 8; ++ct) acc[ct] = (f32x4){0.f, 0.f, 0.f, 0.f};

        #pragma unroll
        for (int ks = 0; ks < 4; ++ks) {
            const int chA = (ks * 4 + lkg) ^ lcol;   // row=lcol's feats
            const bf16x8 afr = *(const bf16x8*)(mG + lcol * ROW + chA * 8);
            #pragma unroll
            for (int ct = 0; ct < 8; ++ct) {
                const int col = ct * 16 + lcol;
                const int chB = (ks * 4 + lkg) ^ (col & 15);
                const bf16x8 bfr = *(const bf16x8*)(&sW[col * ROW + chB * 8]);
                acc[ct] = __builtin_amdgcn_mfma_f32_16x16x32_bf16(
                              afr, bfr, acc[ct], 0, 0, 0);
            }
        }

        // ---- store 16x128: lane (lcol,lkg) -> rows lkg*4+j, col ct*16+lcol
        #pragma unroll
        for (int j = 0; j < 4; ++j) {
            const size_t r = row0 + lkg * 4 + j;
            #pragma unroll
            for (int ct = 0; ct < 8; ++ct)
                out[r * ROW + ct * 16 + lcol] = acc[ct][j] + bv[ct];
        }
    }
}

extern "C" void kernel_launch(void* const* d_in, const int* in_sizes, int n_in,
                              void* d_out, int out_size, void* d_ws, size_t ws_size,
                              hipStream_t stream)
{
    const float* x        = (const float*)d_in[0];
    const float* ln_scale = (const float*)d_in[1];
    const float* rotor    = (const float*)d_in[2];
    const float* w        = (const float*)d_in[3];
    const float* bias     = (const float*)d_in[4];
    float* out = (float*)d_out;
    float* ws  = (float*)d_ws;

    precompute_kernel<<<dim3(2), dim3(1024), 0, stream>>>(rotor, w, ln_scale, ws);

    const int nrows   = in_sizes[0] / (CH * DIM);          // 131072
    const int nblocks = nrows / ROWS_PER_BLOCK;            // 1024

    fused_kernel<<<dim3(nblocks), dim3(BLK), 0, stream>>>(x, bias, ws, out);
}